// Round 15
// baseline (435.732 us; speedup 1.0000x reference)
//
#include <hip/hip_runtime.h>
#include <hip/hip_fp16.h>
#include <math.h>

#define IN_CH 16
#define HC1 128   // H1*C1
#define NH1 4
#define C2 32
#define HID 64
#define NEG 0.2f
#define CAP 10240     // per-bucket capacity (mean ~8450, +20 sigma)
#define CHUNK 4096    // edges per bucket block (16 per thread)

__device__ __forceinline__ float lrelu_exp_fast(float z) {
    float lr = fmaxf(z, NEG * z);   // leaky-relu via max (exact for neg_slope<1)
    return __expf(lr);
}
__device__ __forceinline__ float elu_fast(float v) {
    return v > 0.f ? v : __expf(v) - 1.0f;
}

// v_fma_mix_f32: acc(f32) += f16half(hpack) * w(f32), full f32 fma precision.
__device__ __forceinline__ void fma_mix_lo(float& acc, int hpack, float w) {
    asm("v_fma_mix_f32 %0, %1, %2, %0 op_sel:[0,0,0] op_sel_hi:[1,0,0]"
        : "+v"(acc) : "v"(hpack), "v"(w));
}
__device__ __forceinline__ void fma_mix_hi(float& acc, int hpack, float w) {
    asm("v_fma_mix_f32 %0, %1, %2, %0 op_sel:[1,0,0] op_sel_hi:[1,0,0]"
        : "+v"(acc) : "v"(hpack), "v"(w));
}

// ---- Fused front: bucket-append (blocks [0,nchunk)) + GAT1 attention logits ----
// Logit phase: 4 nodes/wave, W1+att preloaded into registers (R23, proven -15us).
__global__ void k_front(const int* __restrict__ ei, int E, int N, int nchunk,
                        int* __restrict__ cursors, int* __restrict__ buckets,
                        const float* __restrict__ x, const float2* __restrict__ W1v,
                        const float2* __restrict__ att_s2, const float2* __restrict__ att_d2,
                        float* __restrict__ asp, float* __restrict__ adp) {
    int bid = blockIdx.x;
    if (bid < nchunk) {
        __shared__ int cnt[256];
        __shared__ int base[256];
        int t = threadIdx.x;
        int c0 = bid * CHUNK;
        int M = E + N;
        cnt[t] = 0;
        __syncthreads();
        int srcv[16], dstv[16], lp[16];
#pragma unroll
        for (int k = 0; k < 16; ++k) {
            int i = c0 + k * 256 + t;
            int s = -1, d = -1, l = 0;
            if (i < M) {
                if (i < E) { s = ei[i]; d = ei[E + i]; }
                else       { s = d = i - E; }
                l = atomicAdd(&cnt[d >> 8], 1);   // count == local slot
            }
            srcv[k] = s; dstv[k] = d; lp[k] = l;
        }
        __syncthreads();
        if (cnt[t] > 0) base[t] = atomicAdd(&cursors[t], cnt[t]);
        __syncthreads();
#pragma unroll
        for (int k = 0; k < 16; ++k) {
            int d = dstv[k];
            if (d >= 0) {
                int b = d >> 8;
                buckets[b * CAP + base[b] + lp[k]] = (srcv[k] << 8) | (d & 255);
            }
        }
    } else {
        int wave = threadIdx.x >> 6;
        int lane = threadIdx.x & 63;
        int n0 = (bid - nchunk) * 16 + wave * 4;
        if (n0 >= N) return;
        float2 wreg[16];
#pragma unroll
        for (int k = 0; k < 16; ++k) wreg[k] = W1v[k * 64 + lane];
        float2 s2 = att_s2[lane], d2 = att_d2[lane];
        int head = lane >> 4;
        float xv[4];
#pragma unroll
        for (int nd = 0; nd < 4; ++nd) {
            int nx = n0 + nd;
            xv[nd] = x[(size_t)(nx < N ? nx : 0) * IN_CH + (lane & 15)];
        }
#pragma unroll
        for (int nd = 0; nd < 4; ++nd) {
            int nx = n0 + nd;
            if (nx >= N) break;   // wave-uniform (n0-based)
            float ax = 0.f, ay = 0.f;
#pragma unroll
            for (int k = 0; k < 16; ++k) {
                float xk = __shfl(xv[nd], k, 16);
                ax += xk * wreg[k].x;
                ay += xk * wreg[k].y;
            }
            float vs = ax * s2.x + ay * s2.y;
            float vd = ax * d2.x + ay * d2.y;
#pragma unroll
            for (int o = 1; o < 16; o <<= 1) {
                vs += __shfl_xor(vs, o, 64);
                vd += __shfl_xor(vd, o, 64);
            }
            if ((lane & 15) == 0) {
                asp[nx * NH1 + head] = vs;   // node-major [N][4]
                adp[nx * NH1 + head] = vd;
            }
        }
    }
}

// ---- CSR build: TWO blocks per bucket (half-buckets of 128 nodes) ----
// R29: reverted to the R26 half-bucket version (quarter-split was null-to-
// negative: each quarter still scans the full bucket -> 2x scan reads).
__global__ void k_build(const int* __restrict__ buckets, const int* __restrict__ cursors,
                        int N, int M,
                        int* __restrict__ offsets, int* __restrict__ elist) {
    __shared__ int sc[256];
    __shared__ int deg[128];
    __shared__ int cur[128];
    int b = blockIdx.x >> 1, half = blockIdx.x & 1;
    int t = threadIdx.x;
    int cv = cursors[t];
    sc[t] = cv;
    __syncthreads();
    for (int o = 1; o < 256; o <<= 1) {
        int a = (t >= o) ? sc[t - o] : 0;
        __syncthreads();
        sc[t] += a;
        __syncthreads();
    }
    int cnt = cursors[b];
    int gbase_bucket = sc[b] - cnt;
    int n0 = (b << 8) + (half << 7);
    const int* bk = buckets + b * CAP;
    if (t < 128) deg[t] = 0;
    if (blockIdx.x == 0 && t == 0) offsets[N] = M;
    __syncthreads();
    for (int i = t; i < cnt; i += 256) {
        int dl = bk[i] & 255;
        if ((dl >> 7) == half) atomicAdd(&deg[dl & 127], 1);
    }
    __syncthreads();
    int v = (t < 128) ? deg[t] : 0;
    if (t < 128) sc[t] = v;
    __syncthreads();
    for (int o = 1; o < 128; o <<= 1) {
        int a = (t < 128 && t >= o) ? sc[t - o] : 0;
        __syncthreads();
        if (t < 128) sc[t] += a;
        __syncthreads();
    }
    __shared__ int gbh;
    if (t == 127) {
        int S = sc[127];
        gbh = (half == 0) ? gbase_bucket : gbase_bucket + (cnt - S);
    }
    __syncthreads();
    int gbase = gbh;
    if (t < 128) {
        int excl = sc[t] - v;
        cur[t] = excl;
        if (n0 + t < N) offsets[n0 + t] = gbase + excl;
    }
    __syncthreads();
    for (int i = t; i < cnt; i += 256) {
        int e = bk[i];
        int dl = e & 255;
        if ((dl >> 7) == half) {
            int p = atomicAdd(&cur[dl & 127], 1);
            elist[gbase + p] = e >> 8;
        }
    }
}

// ---- FUSED GAT1 aggregation (linearity) + W1 post-mult + ELU + W2 + att2 ----
// R26 geometry (proven 49.9us): 16 lanes/node (4 slots x 4 quads), 4 nodes/wave,
// 2-deep pipeline, aggLds only (4.4KB), W2 direct from L2, no __syncthreads.
__global__ void __launch_bounds__(256)
k_pass(const int* __restrict__ offsets, const int* __restrict__ elist,
       const float4* __restrict__ asp4, const float4* __restrict__ adp4,
       const float4* __restrict__ xrow, int N,
       const float* __restrict__ b1, const float2* __restrict__ W1v,
       const float4* __restrict__ W2q,
       const float* __restrict__ aS2v, const float* __restrict__ aD2v,
       __half2* __restrict__ h2h, float* __restrict__ as2, float* __restrict__ ad2) {
    __shared__ float aggLds[16][68];     // [wave*4+h][node*16 + q*4 + r]; 4.4KB
    int t = threadIdx.x;
    int lane = t & 63;
    int wave = t >> 6;          // 0..3
    int g = lane >> 4;          // node sub-group within wave
    int idx = lane & 15;
    int slot = idx >> 2;        // 4 edge slots
    int cl = idx & 3;           // channel quad (4 floats of the x row)
    int n = blockIdx.x * 16 + wave * 4 + g;
    bool valid = n < N;
    int nn = valid ? n : 0;
    int lo = offsets[nn];
    int hi = valid ? offsets[nn + 1] : lo;
    float4 ad4 = adp4[nn];
    float acc[4][4];            // [head][channel-in-quad]
    float sw[4];
#pragma unroll
    for (int h = 0; h < 4; ++h) {
        sw[h] = 0.f;
#pragma unroll
        for (int j = 0; j < 4; ++j) acc[h][j] = 0.f;
    }
    int iters = (hi - lo + 3) >> 2;   // 4 edges per node per iter

    auto LOAD = [&](int it, unsigned& s, bool& ok) {
        int ee = lo + it * 4 + slot;
        ok = ee < hi;
        s = (unsigned)elist[ok ? ee : lo];
    };
    auto GATHER = [&](unsigned s, float4& xq, float4& zq) {
        xq = xrow[s * 4u + cl];
        zq = asp4[s];
    };
    auto COMPUTE = [&](bool ok, const float4& xq, const float4& zq) {
        float w0 = ok ? lrelu_exp_fast(zq.x + ad4.x) : 0.f;
        float w1 = ok ? lrelu_exp_fast(zq.y + ad4.y) : 0.f;
        float w2 = ok ? lrelu_exp_fast(zq.z + ad4.z) : 0.f;
        float w3 = ok ? lrelu_exp_fast(zq.w + ad4.w) : 0.f;
        acc[0][0] += w0 * xq.x; acc[0][1] += w0 * xq.y; acc[0][2] += w0 * xq.z; acc[0][3] += w0 * xq.w;
        acc[1][0] += w1 * xq.x; acc[1][1] += w1 * xq.y; acc[1][2] += w1 * xq.z; acc[1][3] += w1 * xq.w;
        acc[2][0] += w2 * xq.x; acc[2][1] += w2 * xq.y; acc[2][2] += w2 * xq.z; acc[2][3] += w2 * xq.w;
        acc[3][0] += w3 * xq.x; acc[3][1] += w3 * xq.y; acc[3][2] += w3 * xq.z; acc[3][3] += w3 * xq.w;
        sw[0] += w0; sw[1] += w1; sw[2] += w2; sw[3] += w3;
    };

    if (iters > 0) {
        unsigned sA, sB; bool okA = false, okB = false;
        float4 xA, zA, xB, zB;
        LOAD(0, sA, okA);
        GATHER(sA, xA, zA);
        if (iters > 1) LOAD(1, sB, okB);
        int it = 0;
        for (; it + 2 <= iters; it += 2) {
            GATHER(sB, xB, zB);
            COMPUTE(okA, xA, zA);
            if (it + 2 < iters) { LOAD(it + 2, sA, okA); GATHER(sA, xA, zA); }
            COMPUTE(okB, xB, zB);
            if (it + 3 < iters) LOAD(it + 3, sB, okB);
        }
        if (it < iters) COMPUTE(okA, xA, zA);
    }
    // reduce over the 4 slots (lane bits 2,3)
#pragma unroll
    for (int h = 0; h < 4; ++h) {
#pragma unroll
        for (int j = 0; j < 4; ++j) {
            acc[h][j] += __shfl_xor(acc[h][j], 4, 64);
            acc[h][j] += __shfl_xor(acc[h][j], 8, 64);
        }
        sw[h] += __shfl_xor(sw[h], 4, 64);
        sw[h] += __shfl_xor(sw[h], 8, 64);
    }
    if (slot == 0) {
#pragma unroll
        for (int h = 0; h < 4; ++h) {
            float inv = 1.f / (sw[h] + 1e-16f);
            *(float4*)&aggLds[wave * 4 + h][g * 16 + cl * 4] =
                make_float4(acc[h][0] * inv, acc[h][1] * inv,
                            acc[h][2] * inv, acc[h][3] * inv);
        }
    }
    __builtin_amdgcn_wave_barrier();

    // ---- mix phase: W1 post-mult + bias + ELU + W2 (direct L2) + att2 ----
    int h = lane >> 4;                 // head of this lane's two h1-channels
    float2 w1reg[16];
#pragma unroll
    for (int c = 0; c < 16; ++c) w1reg[c] = W1v[c * 64 + lane];
    float2 bv = *(const float2*)(b1 + 2 * lane);
    int n0 = blockIdx.x * 16 + wave * 4;
    if (n0 >= N) return;
    float ev0[4], ev1[4];
#pragma unroll
    for (int nd = 0; nd < 4; ++nd) {
        int nx = n0 + nd;
        float s0 = 0.f, s1 = 0.f;
        if (nx < N) {
#pragma unroll
            for (int q = 0; q < 4; ++q) {
                float4 aq = *(const float4*)&aggLds[wave * 4 + h][nd * 16 + q * 4];
                const float* ap = (const float*)&aq;
#pragma unroll
                for (int r = 0; r < 4; ++r) {
                    int c = q * 4 + r;
                    s0 += ap[r] * w1reg[c].x;
                    s1 += ap[r] * w1reg[c].y;
                }
            }
        }
        ev0[nd] = elu_fast(s0 + bv.x);
        ev1[nd] = elu_fast(s1 + bv.y);
    }
    int c4g = lane & 7, kh = lane >> 3;
    float gg[4][4];
#pragma unroll
    for (int nd = 0; nd < 4; ++nd)
#pragma unroll
        for (int j = 0; j < 4; ++j) gg[nd][j] = 0.f;
#pragma unroll
    for (int kk = 0; kk < 16; ++kk) {
        int k = kh * 16 + kk;
        float4 wv = W2q[(k << 3) | c4g];   // direct L2 read, broadcast-friendly
#pragma unroll
        for (int nd = 0; nd < 4; ++nd) {
            float xk = __shfl((kk & 1) ? ev1[nd] : ev0[nd], k >> 1, 64);
            gg[nd][0] += xk * wv.x; gg[nd][1] += xk * wv.y;
            gg[nd][2] += xk * wv.z; gg[nd][3] += xk * wv.w;
        }
    }
#pragma unroll
    for (int nd = 0; nd < 4; ++nd)
#pragma unroll
        for (int j = 0; j < 4; ++j) {
            gg[nd][j] += __shfl_xor(gg[nd][j], 8, 64);
            gg[nd][j] += __shfl_xor(gg[nd][j], 16, 64);
            gg[nd][j] += __shfl_xor(gg[nd][j], 32, 64);
        }
    if (lane < 8) {
        int c4 = c4g * 4;
#pragma unroll
        for (int nd = 0; nd < 4; ++nd) {
            int nx = n0 + nd;
            if (nx >= N) break;
            h2h[(size_t)nx * 16 + (c4 >> 1)]     = __floats2half2_rn(gg[nd][0], gg[nd][1]);
            h2h[(size_t)nx * 16 + (c4 >> 1) + 1] = __floats2half2_rn(gg[nd][2], gg[nd][3]);
            float ps = gg[nd][0] * aS2v[c4] + gg[nd][1] * aS2v[c4 + 1]
                     + gg[nd][2] * aS2v[c4 + 2] + gg[nd][3] * aS2v[c4 + 3];
            float pd = gg[nd][0] * aD2v[c4] + gg[nd][1] * aD2v[c4 + 1]
                     + gg[nd][2] * aD2v[c4 + 2] + gg[nd][3] * aD2v[c4 + 3];
            ps += __shfl_xor(ps, 1, 64); ps += __shfl_xor(ps, 2, 64); ps += __shfl_xor(ps, 4, 64);
            pd += __shfl_xor(pd, 1, 64); pd += __shfl_xor(pd, 2, 64); pd += __shfl_xor(pd, 4, 64);
            if (lane == 0) { as2[nx] = ps; ad2[nx] = pd; }
        }
    }
}

// ---- GAT2 aggregation: node-per-16-lanes, 2-deep pipeline ----
// R29: FUSED POOLING — ELU'd per-node output is atomically accumulated into
// per-graph psum[G][32] (nodes sorted by graph; segment-sum = atomic adds,
// ~500 adds/address over 3200 L2 addresses). out2 (12.8MB round-trip) and
// the k_pool scan are eliminated; tiny k_head does mean+MLP.
__global__ void __launch_bounds__(256)
k_agg2(const int* __restrict__ offsets, const int* __restrict__ elist,
       const char* __restrict__ as2b, const float* __restrict__ ad2,
       const char* __restrict__ h2b, const float* __restrict__ b2,
       const int* __restrict__ batch, int N, float* __restrict__ psum) {
    int t = threadIdx.x;
    int lane = t & 63;
    int g = lane >> 4;
    int idx = lane & 15;
    int slot = idx >> 2;
    int chunk = idx & 3;
    int n = blockIdx.x * 16 + (t >> 6) * 4 + g;
    bool valid = n < N;
    int nn = valid ? n : 0;
    int lo = offsets[nn];
    int hi = valid ? offsets[nn + 1] : lo;
    float ad = ad2[nn];
    unsigned coff = (unsigned)(chunk << 4);
    int ebase = lo + slot * 4;
    float acc[8];
#pragma unroll
    for (int j = 0; j < 8; ++j) acc[j] = 0.f;
    float sumw = 0.f;
    int iters = (hi - lo + 15) >> 4;

    auto LOAD_S = [&](int it, unsigned* s, bool* ok) {
#pragma unroll
        for (int u = 0; u < 4; ++u) {
            int ee = ebase + it * 16 + u;
            ok[u] = ee < hi;
            s[u] = (unsigned)elist[ok[u] ? ee : lo];
        }
    };
    auto LOAD_ZV = [&](const unsigned* s, float* z, float4* v) {
#pragma unroll
        for (int u = 0; u < 4; ++u) {
            z[u] = *(const float*)(as2b + (s[u] * 4u));
            v[u] = *(const float4*)(h2b + (s[u] * 64u + coff));
        }
    };
    auto COMPUTE = [&](const bool* ok, const float* z, const float4* v) {
#pragma unroll
        for (int u = 0; u < 4; ++u) {
            float w = ok[u] ? lrelu_exp_fast(z[u] + ad) : 0.f;
            const int* hp = (const int*)&v[u];
            fma_mix_lo(acc[0], hp[0], w); fma_mix_hi(acc[1], hp[0], w);
            fma_mix_lo(acc[2], hp[1], w); fma_mix_hi(acc[3], hp[1], w);
            fma_mix_lo(acc[4], hp[2], w); fma_mix_hi(acc[5], hp[2], w);
            fma_mix_lo(acc[6], hp[3], w); fma_mix_hi(acc[7], hp[3], w);
            sumw += w;
        }
    };

    if (iters > 0) {
        unsigned sA[4], sB[4]; bool okA[4], okB[4];
        float zA[4], zB[4]; float4 vA[4], vB[4];
        LOAD_S(0, sA, okA);
        LOAD_ZV(sA, zA, vA);
        if (iters > 1) LOAD_S(1, sB, okB);
        int it = 0;
        for (; it + 2 <= iters; it += 2) {
            LOAD_ZV(sB, zB, vB);
            COMPUTE(okA, zA, vA);
            if (it + 2 < iters) {
                LOAD_S(it + 2, sA, okA);
                LOAD_ZV(sA, zA, vA);
            }
            COMPUTE(okB, zB, vB);
            if (it + 3 < iters) LOAD_S(it + 3, sB, okB);
        }
        if (it < iters) COMPUTE(okA, zA, vA);
    }
#pragma unroll
    for (int j = 0; j < 8; ++j) {
        acc[j] += __shfl_xor(acc[j], 4, 64);
        acc[j] += __shfl_xor(acc[j], 8, 64);
    }
    sumw += __shfl_xor(sumw, 4, 64);
    sumw += __shfl_xor(sumw, 8, 64);
    if (slot == 0 && valid) {
        float inv = 1.f / (sumw + 1e-16f);
        float4 ba = ((const float4*)b2)[2 * chunk];
        float4 bb = ((const float4*)b2)[2 * chunk + 1];
        float o[8];
        o[0] = elu_fast(acc[0] * inv + ba.x); o[1] = elu_fast(acc[1] * inv + ba.y);
        o[2] = elu_fast(acc[2] * inv + ba.z); o[3] = elu_fast(acc[3] * inv + ba.w);
        o[4] = elu_fast(acc[4] * inv + bb.x); o[5] = elu_fast(acc[5] * inv + bb.y);
        o[6] = elu_fast(acc[6] * inv + bb.z); o[7] = elu_fast(acc[7] * inv + bb.w);
        int gId = batch[n];
        float* dst = psum + (size_t)gId * C2 + 8 * chunk;
#pragma unroll
        for (int j = 0; j < 8; ++j) atomicAdd(dst + j, o[j]);
    }
}

// ---- per-graph mean + MLP head (1 wave per graph) ----
__global__ void k_head(const float* __restrict__ psum, const int* __restrict__ batch,
                       int N, const float* __restrict__ Wh1, const float* __restrict__ bh1,
                       const float* __restrict__ Wh2, const float* __restrict__ bh2,
                       float* __restrict__ out) {
    int g = blockIdx.x;
    int lane = threadIdx.x;     // 64 threads = 1 wave
    __shared__ int sb[2];
    if (lane < 2) {
        int target = g + lane;
        int lo = 0, hi = N;
        while (lo < hi) { int mid = (lo + hi) >> 1; if (batch[mid] < target) lo = mid + 1; else hi = mid; }
        sb[lane] = lo;
    }
    __syncthreads();
    float cnt = (float)(sb[1] - sb[0]);
    float inv = 1.f / fmaxf(cnt, 1.f);
    float pv = (lane < C2) ? psum[(size_t)g * C2 + lane] * inv : 0.f;
    float a = bh1[lane];
#pragma unroll
    for (int c = 0; c < C2; ++c) a += __shfl(pv, c, 64) * Wh1[c * HID + lane];
    float hval = fmaxf(a, 0.f) * Wh2[lane];
    for (int o = 32; o > 0; o >>= 1) hval += __shfl_down(hval, o, 64);
    if (lane == 0) out[g] = hval + bh2[0];
}

extern "C" void kernel_launch(void* const* d_in, const int* in_sizes, int n_in,
                              void* d_out, int out_size, void* d_ws, size_t ws_size,
                              hipStream_t stream) {
    const float* x    = (const float*)d_in[0];
    const int*   ei   = (const int*)d_in[1];
    const int*   batch= (const int*)d_in[2];
    const float* W1   = (const float*)d_in[3];
    const float* aS1  = (const float*)d_in[4];
    const float* aD1  = (const float*)d_in[5];
    const float* b1   = (const float*)d_in[6];
    const float* W2   = (const float*)d_in[7];
    const float* aS2  = (const float*)d_in[8];
    const float* aD2  = (const float*)d_in[9];
    const float* b2   = (const float*)d_in[10];
    const float* Wh1  = (const float*)d_in[11];
    const float* bh1  = (const float*)d_in[12];
    const float* Wh2  = (const float*)d_in[13];
    const float* bh2  = (const float*)d_in[14];
    float* out = (float*)d_out;

    int N = in_sizes[2];
    int E = in_sizes[1] / 2;
    int M = E + N;
    int G = out_size;
    int nbk = (N + 255) >> 8;
    int nchunk = (M + CHUNK - 1) / CHUNK;
    int nlin = (N + 15) / 16;   // 4 nodes/wave x 4 waves

    char* p = (char*)d_ws;
    auto alloc = [&](size_t bytes) -> void* {
        void* r = (void*)p;
        p += (bytes + 255) & ~(size_t)255;
        return r;
    };
    float* asp     = (float*)alloc((size_t)N * NH1 * 4);    // [N][4] node-major logits
    float* adp     = (float*)alloc((size_t)N * NH1 * 4);    // [N][4]
    __half2* h2h   = (__half2*)alloc((size_t)N * 16 * 4);   // N x 32 fp16
    float* as2     = (float*)alloc((size_t)N * 4);
    float* ad2     = (float*)alloc((size_t)N * 4);
    float* psum    = (float*)alloc((size_t)G * C2 * 4);     // per-graph pooled sums
    int*   offsets = (int*)alloc((size_t)(N + 1) * 4);
    int*   elist   = (int*)alloc((size_t)M * 4);
    int*   cursors = (int*)alloc(256 * 4);
    int*   buckets = (int*)alloc((size_t)nbk * CAP * 4);

    hipMemsetAsync(cursors, 0, 256 * 4, stream);
    hipMemsetAsync(psum, 0, (size_t)G * C2 * 4, stream);
    k_front<<<nchunk + nlin, 256, 0, stream>>>(ei, E, N, nchunk, cursors, buckets,
                                               x, (const float2*)W1, (const float2*)aS1,
                                               (const float2*)aD1, asp, adp);
    k_build<<<2 * nbk, 256, 0, stream>>>(buckets, cursors, N, M, offsets, elist);
    int nblk16 = (N + 15) / 16;
    k_pass<<<nblk16, 256, 0, stream>>>(offsets, elist, (const float4*)asp,
                                       (const float4*)adp, (const float4*)x, N,
                                       b1, (const float2*)W1, (const float4*)W2,
                                       aS2, aD2, h2h, as2, ad2);
    k_agg2<<<nblk16, 256, 0, stream>>>(offsets, elist, (const char*)as2, ad2,
                                       (const char*)h2h, b2, batch, N, psum);
    k_head<<<G, 64, 0, stream>>>(psum, batch, N, Wh1, bh1, Wh2, bh2, out);
}

// Round 16
// 229.098 us; speedup vs baseline: 1.9019x; 1.9019x over previous
//
#include <hip/hip_runtime.h>
#include <hip/hip_fp16.h>
#include <math.h>

#define IN_CH 16
#define HC1 128   // H1*C1
#define NH1 4
#define C2 32
#define HID 64
#define NEG 0.2f
#define CAP 10240     // per-bucket capacity (mean ~8450, +20 sigma)
#define CHUNK 4096    // edges per bucket block (16 per thread)

__device__ __forceinline__ float lrelu_exp_fast(float z) {
    float lr = fmaxf(z, NEG * z);   // leaky-relu via max (exact for neg_slope<1)
    return __expf(lr);
}
__device__ __forceinline__ float elu_fast(float v) {
    return v > 0.f ? v : __expf(v) - 1.0f;
}

// v_fma_mix_f32: acc(f32) += f16half(hpack) * w(f32), full f32 fma precision.
__device__ __forceinline__ void fma_mix_lo(float& acc, int hpack, float w) {
    asm("v_fma_mix_f32 %0, %1, %2, %0 op_sel:[0,0,0] op_sel_hi:[1,0,0]"
        : "+v"(acc) : "v"(hpack), "v"(w));
}
__device__ __forceinline__ void fma_mix_hi(float& acc, int hpack, float w) {
    asm("v_fma_mix_f32 %0, %1, %2, %0 op_sel:[1,0,0] op_sel_hi:[1,0,0]"
        : "+v"(acc) : "v"(hpack), "v"(w));
}

// ---- Fused front: bucket-append (blocks [0,nchunk)) + GAT1 attention logits ----
// Logit phase: 4 nodes/wave, W1+att preloaded into registers (R23, proven -15us).
__global__ void k_front(const int* __restrict__ ei, int E, int N, int nchunk,
                        int* __restrict__ cursors, int* __restrict__ buckets,
                        const float* __restrict__ x, const float2* __restrict__ W1v,
                        const float2* __restrict__ att_s2, const float2* __restrict__ att_d2,
                        float* __restrict__ asp, float* __restrict__ adp) {
    int bid = blockIdx.x;
    if (bid < nchunk) {
        __shared__ int cnt[256];
        __shared__ int base[256];
        int t = threadIdx.x;
        int c0 = bid * CHUNK;
        int M = E + N;
        cnt[t] = 0;
        __syncthreads();
        int srcv[16], dstv[16], lp[16];
#pragma unroll
        for (int k = 0; k < 16; ++k) {
            int i = c0 + k * 256 + t;
            int s = -1, d = -1, l = 0;
            if (i < M) {
                if (i < E) { s = ei[i]; d = ei[E + i]; }
                else       { s = d = i - E; }
                l = atomicAdd(&cnt[d >> 8], 1);   // count == local slot
            }
            srcv[k] = s; dstv[k] = d; lp[k] = l;
        }
        __syncthreads();
        if (cnt[t] > 0) base[t] = atomicAdd(&cursors[t], cnt[t]);
        __syncthreads();
#pragma unroll
        for (int k = 0; k < 16; ++k) {
            int d = dstv[k];
            if (d >= 0) {
                int b = d >> 8;
                buckets[b * CAP + base[b] + lp[k]] = (srcv[k] << 8) | (d & 255);
            }
        }
    } else {
        int wave = threadIdx.x >> 6;
        int lane = threadIdx.x & 63;
        int n0 = (bid - nchunk) * 16 + wave * 4;
        if (n0 >= N) return;
        float2 wreg[16];
#pragma unroll
        for (int k = 0; k < 16; ++k) wreg[k] = W1v[k * 64 + lane];
        float2 s2 = att_s2[lane], d2 = att_d2[lane];
        int head = lane >> 4;
        float xv[4];
#pragma unroll
        for (int nd = 0; nd < 4; ++nd) {
            int nx = n0 + nd;
            xv[nd] = x[(size_t)(nx < N ? nx : 0) * IN_CH + (lane & 15)];
        }
#pragma unroll
        for (int nd = 0; nd < 4; ++nd) {
            int nx = n0 + nd;
            if (nx >= N) break;   // wave-uniform (n0-based)
            float ax = 0.f, ay = 0.f;
#pragma unroll
            for (int k = 0; k < 16; ++k) {
                float xk = __shfl(xv[nd], k, 16);
                ax += xk * wreg[k].x;
                ay += xk * wreg[k].y;
            }
            float vs = ax * s2.x + ay * s2.y;
            float vd = ax * d2.x + ay * d2.y;
#pragma unroll
            for (int o = 1; o < 16; o <<= 1) {
                vs += __shfl_xor(vs, o, 64);
                vd += __shfl_xor(vd, o, 64);
            }
            if ((lane & 15) == 0) {
                asp[nx * NH1 + head] = vs;   // node-major [N][4]
                adp[nx * NH1 + head] = vd;
            }
        }
    }
}

// ---- CSR build: TWO blocks per bucket (half-buckets of 128 nodes) ----
__global__ void k_build(const int* __restrict__ buckets, const int* __restrict__ cursors,
                        int N, int M,
                        int* __restrict__ offsets, int* __restrict__ elist) {
    __shared__ int sc[256];
    __shared__ int deg[128];
    __shared__ int cur[128];
    int b = blockIdx.x >> 1, half = blockIdx.x & 1;
    int t = threadIdx.x;
    int cv = cursors[t];
    sc[t] = cv;
    __syncthreads();
    for (int o = 1; o < 256; o <<= 1) {
        int a = (t >= o) ? sc[t - o] : 0;
        __syncthreads();
        sc[t] += a;
        __syncthreads();
    }
    int cnt = cursors[b];
    int gbase_bucket = sc[b] - cnt;
    int n0 = (b << 8) + (half << 7);
    const int* bk = buckets + b * CAP;
    if (t < 128) deg[t] = 0;
    if (blockIdx.x == 0 && t == 0) offsets[N] = M;
    __syncthreads();
    for (int i = t; i < cnt; i += 256) {
        int dl = bk[i] & 255;
        if ((dl >> 7) == half) atomicAdd(&deg[dl & 127], 1);
    }
    __syncthreads();
    int v = (t < 128) ? deg[t] : 0;
    if (t < 128) sc[t] = v;
    __syncthreads();
    for (int o = 1; o < 128; o <<= 1) {
        int a = (t < 128 && t >= o) ? sc[t - o] : 0;
        __syncthreads();
        if (t < 128) sc[t] += a;
        __syncthreads();
    }
    __shared__ int gbh;
    if (t == 127) {
        int S = sc[127];
        gbh = (half == 0) ? gbase_bucket : gbase_bucket + (cnt - S);
    }
    __syncthreads();
    int gbase = gbh;
    if (t < 128) {
        int excl = sc[t] - v;
        cur[t] = excl;
        if (n0 + t < N) offsets[n0 + t] = gbase + excl;
    }
    __syncthreads();
    for (int i = t; i < cnt; i += 256) {
        int e = bk[i];
        int dl = e & 255;
        if ((dl >> 7) == half) {
            int p = atomicAdd(&cur[dl & 127], 1);
            elist[gbase + p] = e >> 8;
        }
    }
}

// ---- FUSED GAT1 aggregation (linearity) + W1 post-mult + ELU + W2 + att2 ----
// R26 geometry (verified best, 49.9us / 230.25 total): 16 lanes/node (4 slots
// x 4 quads), 4 nodes/wave, 2-deep pipeline, aggLds only (4.6KB), W2 direct
// from L2, no __syncthreads.
__global__ void __launch_bounds__(256)
k_pass(const int* __restrict__ offsets, const int* __restrict__ elist,
       const float4* __restrict__ asp4, const float4* __restrict__ adp4,
       const float4* __restrict__ xrow, int N,
       const float* __restrict__ b1, const float2* __restrict__ W1v,
       const float4* __restrict__ W2q,
       const float* __restrict__ aS2v, const float* __restrict__ aD2v,
       __half2* __restrict__ h2h, float* __restrict__ as2, float* __restrict__ ad2) {
    __shared__ float aggLds[16][68];     // [wave*4+h][node*16 + q*4 + r]; 4.4KB
    int t = threadIdx.x;
    int lane = t & 63;
    int wave = t >> 6;          // 0..3
    int g = lane >> 4;          // node sub-group within wave
    int idx = lane & 15;
    int slot = idx >> 2;        // 4 edge slots
    int cl = idx & 3;           // channel quad (4 floats of the x row)
    int n = blockIdx.x * 16 + wave * 4 + g;
    bool valid = n < N;
    int nn = valid ? n : 0;
    int lo = offsets[nn];
    int hi = valid ? offsets[nn + 1] : lo;
    float4 ad4 = adp4[nn];
    float acc[4][4];            // [head][channel-in-quad]
    float sw[4];
#pragma unroll
    for (int h = 0; h < 4; ++h) {
        sw[h] = 0.f;
#pragma unroll
        for (int j = 0; j < 4; ++j) acc[h][j] = 0.f;
    }
    int iters = (hi - lo + 3) >> 2;   // 4 edges per node per iter

    auto LOAD = [&](int it, unsigned& s, bool& ok) {
        int ee = lo + it * 4 + slot;
        ok = ee < hi;
        s = (unsigned)elist[ok ? ee : lo];
    };
    auto GATHER = [&](unsigned s, float4& xq, float4& zq) {
        xq = xrow[s * 4u + cl];
        zq = asp4[s];
    };
    auto COMPUTE = [&](bool ok, const float4& xq, const float4& zq) {
        float w0 = ok ? lrelu_exp_fast(zq.x + ad4.x) : 0.f;
        float w1 = ok ? lrelu_exp_fast(zq.y + ad4.y) : 0.f;
        float w2 = ok ? lrelu_exp_fast(zq.z + ad4.z) : 0.f;
        float w3 = ok ? lrelu_exp_fast(zq.w + ad4.w) : 0.f;
        acc[0][0] += w0 * xq.x; acc[0][1] += w0 * xq.y; acc[0][2] += w0 * xq.z; acc[0][3] += w0 * xq.w;
        acc[1][0] += w1 * xq.x; acc[1][1] += w1 * xq.y; acc[1][2] += w1 * xq.z; acc[1][3] += w1 * xq.w;
        acc[2][0] += w2 * xq.x; acc[2][1] += w2 * xq.y; acc[2][2] += w2 * xq.z; acc[2][3] += w2 * xq.w;
        acc[3][0] += w3 * xq.x; acc[3][1] += w3 * xq.y; acc[3][2] += w3 * xq.z; acc[3][3] += w3 * xq.w;
        sw[0] += w0; sw[1] += w1; sw[2] += w2; sw[3] += w3;
    };

    if (iters > 0) {
        unsigned sA, sB; bool okA = false, okB = false;
        float4 xA, zA, xB, zB;
        LOAD(0, sA, okA);
        GATHER(sA, xA, zA);
        if (iters > 1) LOAD(1, sB, okB);
        int it = 0;
        for (; it + 2 <= iters; it += 2) {
            GATHER(sB, xB, zB);
            COMPUTE(okA, xA, zA);
            if (it + 2 < iters) { LOAD(it + 2, sA, okA); GATHER(sA, xA, zA); }
            COMPUTE(okB, xB, zB);
            if (it + 3 < iters) LOAD(it + 3, sB, okB);
        }
        if (it < iters) COMPUTE(okA, xA, zA);
    }
    // reduce over the 4 slots (lane bits 2,3)
#pragma unroll
    for (int h = 0; h < 4; ++h) {
#pragma unroll
        for (int j = 0; j < 4; ++j) {
            acc[h][j] += __shfl_xor(acc[h][j], 4, 64);
            acc[h][j] += __shfl_xor(acc[h][j], 8, 64);
        }
        sw[h] += __shfl_xor(sw[h], 4, 64);
        sw[h] += __shfl_xor(sw[h], 8, 64);
    }
    if (slot == 0) {
#pragma unroll
        for (int h = 0; h < 4; ++h) {
            float inv = 1.f / (sw[h] + 1e-16f);
            *(float4*)&aggLds[wave * 4 + h][g * 16 + cl * 4] =
                make_float4(acc[h][0] * inv, acc[h][1] * inv,
                            acc[h][2] * inv, acc[h][3] * inv);
        }
    }
    __builtin_amdgcn_wave_barrier();

    // ---- mix phase: W1 post-mult + bias + ELU + W2 (direct L2) + att2 ----
    int h = lane >> 4;                 // head of this lane's two h1-channels
    float2 w1reg[16];
#pragma unroll
    for (int c = 0; c < 16; ++c) w1reg[c] = W1v[c * 64 + lane];
    float2 bv = *(const float2*)(b1 + 2 * lane);
    int n0 = blockIdx.x * 16 + wave * 4;
    if (n0 >= N) return;
    float ev0[4], ev1[4];
#pragma unroll
    for (int nd = 0; nd < 4; ++nd) {
        int nx = n0 + nd;
        float s0 = 0.f, s1 = 0.f;
        if (nx < N) {
#pragma unroll
            for (int q = 0; q < 4; ++q) {
                float4 aq = *(const float4*)&aggLds[wave * 4 + h][nd * 16 + q * 4];
                const float* ap = (const float*)&aq;
#pragma unroll
                for (int r = 0; r < 4; ++r) {
                    int c = q * 4 + r;
                    s0 += ap[r] * w1reg[c].x;
                    s1 += ap[r] * w1reg[c].y;
                }
            }
        }
        ev0[nd] = elu_fast(s0 + bv.x);
        ev1[nd] = elu_fast(s1 + bv.y);
    }
    int c4g = lane & 7, kh = lane >> 3;
    float gg[4][4];
#pragma unroll
    for (int nd = 0; nd < 4; ++nd)
#pragma unroll
        for (int j = 0; j < 4; ++j) gg[nd][j] = 0.f;
#pragma unroll
    for (int kk = 0; kk < 16; ++kk) {
        int k = kh * 16 + kk;
        float4 wv = W2q[(k << 3) | c4g];   // direct L2 read, broadcast-friendly
#pragma unroll
        for (int nd = 0; nd < 4; ++nd) {
            float xk = __shfl((kk & 1) ? ev1[nd] : ev0[nd], k >> 1, 64);
            gg[nd][0] += xk * wv.x; gg[nd][1] += xk * wv.y;
            gg[nd][2] += xk * wv.z; gg[nd][3] += xk * wv.w;
        }
    }
#pragma unroll
    for (int nd = 0; nd < 4; ++nd)
#pragma unroll
        for (int j = 0; j < 4; ++j) {
            gg[nd][j] += __shfl_xor(gg[nd][j], 8, 64);
            gg[nd][j] += __shfl_xor(gg[nd][j], 16, 64);
            gg[nd][j] += __shfl_xor(gg[nd][j], 32, 64);
        }
    if (lane < 8) {
        int c4 = c4g * 4;
#pragma unroll
        for (int nd = 0; nd < 4; ++nd) {
            int nx = n0 + nd;
            if (nx >= N) break;
            h2h[(size_t)nx * 16 + (c4 >> 1)]     = __floats2half2_rn(gg[nd][0], gg[nd][1]);
            h2h[(size_t)nx * 16 + (c4 >> 1) + 1] = __floats2half2_rn(gg[nd][2], gg[nd][3]);
            float ps = gg[nd][0] * aS2v[c4] + gg[nd][1] * aS2v[c4 + 1]
                     + gg[nd][2] * aS2v[c4 + 2] + gg[nd][3] * aS2v[c4 + 3];
            float pd = gg[nd][0] * aD2v[c4] + gg[nd][1] * aD2v[c4 + 1]
                     + gg[nd][2] * aD2v[c4 + 2] + gg[nd][3] * aD2v[c4 + 3];
            ps += __shfl_xor(ps, 1, 64); ps += __shfl_xor(ps, 2, 64); ps += __shfl_xor(ps, 4, 64);
            pd += __shfl_xor(pd, 1, 64); pd += __shfl_xor(pd, 2, 64); pd += __shfl_xor(pd, 4, 64);
            if (lane == 0) { as2[nx] = ps; ad2[nx] = pd; }
        }
    }
}

// ---- GAT2 aggregation: node-per-16-lanes, 2-deep pipeline ----
__global__ void __launch_bounds__(256)
k_agg2(const int* __restrict__ offsets, const int* __restrict__ elist,
       const char* __restrict__ as2b, const float* __restrict__ ad2,
       const char* __restrict__ h2b, const float* __restrict__ b2,
       int N, float* __restrict__ out2) {
    int t = threadIdx.x;
    int lane = t & 63;
    int g = lane >> 4;
    int idx = lane & 15;
    int slot = idx >> 2;
    int chunk = idx & 3;
    int n = blockIdx.x * 16 + (t >> 6) * 4 + g;
    bool valid = n < N;
    int nn = valid ? n : 0;
    int lo = offsets[nn];
    int hi = valid ? offsets[nn + 1] : lo;
    float ad = ad2[nn];
    unsigned coff = (unsigned)(chunk << 4);
    int ebase = lo + slot * 4;
    float acc[8];
#pragma unroll
    for (int j = 0; j < 8; ++j) acc[j] = 0.f;
    float sumw = 0.f;
    int iters = (hi - lo + 15) >> 4;

    auto LOAD_S = [&](int it, unsigned* s, bool* ok) {
#pragma unroll
        for (int u = 0; u < 4; ++u) {
            int ee = ebase + it * 16 + u;
            ok[u] = ee < hi;
            s[u] = (unsigned)elist[ok[u] ? ee : lo];
        }
    };
    auto LOAD_ZV = [&](const unsigned* s, float* z, float4* v) {
#pragma unroll
        for (int u = 0; u < 4; ++u) {
            z[u] = *(const float*)(as2b + (s[u] * 4u));
            v[u] = *(const float4*)(h2b + (s[u] * 64u + coff));
        }
    };
    auto COMPUTE = [&](const bool* ok, const float* z, const float4* v) {
#pragma unroll
        for (int u = 0; u < 4; ++u) {
            float w = ok[u] ? lrelu_exp_fast(z[u] + ad) : 0.f;
            const int* hp = (const int*)&v[u];
            fma_mix_lo(acc[0], hp[0], w); fma_mix_hi(acc[1], hp[0], w);
            fma_mix_lo(acc[2], hp[1], w); fma_mix_hi(acc[3], hp[1], w);
            fma_mix_lo(acc[4], hp[2], w); fma_mix_hi(acc[5], hp[2], w);
            fma_mix_lo(acc[6], hp[3], w); fma_mix_hi(acc[7], hp[3], w);
            sumw += w;
        }
    };

    if (iters > 0) {
        unsigned sA[4], sB[4]; bool okA[4], okB[4];
        float zA[4], zB[4]; float4 vA[4], vB[4];
        LOAD_S(0, sA, okA);
        LOAD_ZV(sA, zA, vA);
        if (iters > 1) LOAD_S(1, sB, okB);
        int it = 0;
        for (; it + 2 <= iters; it += 2) {
            LOAD_ZV(sB, zB, vB);
            COMPUTE(okA, zA, vA);
            if (it + 2 < iters) {
                LOAD_S(it + 2, sA, okA);
                LOAD_ZV(sA, zA, vA);
            }
            COMPUTE(okB, zB, vB);
            if (it + 3 < iters) LOAD_S(it + 3, sB, okB);
        }
        if (it < iters) COMPUTE(okA, zA, vA);
    }
#pragma unroll
    for (int j = 0; j < 8; ++j) {
        acc[j] += __shfl_xor(acc[j], 4, 64);
        acc[j] += __shfl_xor(acc[j], 8, 64);
    }
    sumw += __shfl_xor(sumw, 4, 64);
    sumw += __shfl_xor(sumw, 8, 64);
    if (slot == 0 && valid) {
        float inv = 1.f / (sumw + 1e-16f);
        float4 ba = ((const float4*)b2)[2 * chunk];
        float4 bb = ((const float4*)b2)[2 * chunk + 1];
        float o[8];
        o[0] = elu_fast(acc[0] * inv + ba.x); o[1] = elu_fast(acc[1] * inv + ba.y);
        o[2] = elu_fast(acc[2] * inv + ba.z); o[3] = elu_fast(acc[3] * inv + ba.w);
        o[4] = elu_fast(acc[4] * inv + bb.x); o[5] = elu_fast(acc[5] * inv + bb.y);
        o[6] = elu_fast(acc[6] * inv + bb.z); o[7] = elu_fast(acc[7] * inv + bb.w);
        float* dst = out2 + (size_t)n * C2 + 8 * chunk;
        *(float4*)dst = make_float4(o[0], o[1], o[2], o[3]);
        *(float4*)(dst + 4) = make_float4(o[4], o[5], o[6], o[7]);
    }
}

// ---- mean-pool per graph + MLP head ----
__global__ void k_pool(const float* __restrict__ out2, const int* __restrict__ batch,
                       int N, const float* __restrict__ Wh1, const float* __restrict__ bh1,
                       const float* __restrict__ Wh2, const float* __restrict__ bh2,
                       float* __restrict__ out) {
    int g = blockIdx.x;
    int t = threadIdx.x;
    __shared__ int sb[2];
    __shared__ float pooled[C2];
    __shared__ float red[256];
    if (t < 2) {
        int target = g + t;
        int lo = 0, hi = N;
        while (lo < hi) { int mid = (lo + hi) >> 1; if (batch[mid] < target) lo = mid + 1; else hi = mid; }
        sb[t] = lo;
    }
    __syncthreads();
    int lo = sb[0], hi = sb[1];
    int c = t & 31, grp = t >> 5;
    float part = 0.f;
    for (int n = lo + grp; n < hi; n += 8) part += out2[n * C2 + c];
    red[t] = part;
    __syncthreads();
    if (t < 128) red[t] += red[t + 128];
    __syncthreads();
    if (t < 64) red[t] += red[t + 64];
    __syncthreads();
    if (t < 32) {
        red[t] += red[t + 32];
        float cnt = (float)(hi - lo);
        pooled[t] = red[t] / fmaxf(cnt, 1.f);
    }
    __syncthreads();
    float hval = 0.f;
    if (t < HID) {
        float a = bh1[t];
#pragma unroll
        for (int cc = 0; cc < C2; ++cc) a += pooled[cc] * Wh1[cc * HID + t];
        hval = fmaxf(a, 0.f) * Wh2[t];
    }
    if (t < 64) {
        for (int o = 32; o > 0; o >>= 1) hval += __shfl_down(hval, o, 64);
        if (t == 0) out[g] = hval + bh2[0];
    }
}

extern "C" void kernel_launch(void* const* d_in, const int* in_sizes, int n_in,
                              void* d_out, int out_size, void* d_ws, size_t ws_size,
                              hipStream_t stream) {
    const float* x    = (const float*)d_in[0];
    const int*   ei   = (const int*)d_in[1];
    const int*   batch= (const int*)d_in[2];
    const float* W1   = (const float*)d_in[3];
    const float* aS1  = (const float*)d_in[4];
    const float* aD1  = (const float*)d_in[5];
    const float* b1   = (const float*)d_in[6];
    const float* W2   = (const float*)d_in[7];
    const float* aS2  = (const float*)d_in[8];
    const float* aD2  = (const float*)d_in[9];
    const float* b2   = (const float*)d_in[10];
    const float* Wh1  = (const float*)d_in[11];
    const float* bh1  = (const float*)d_in[12];
    const float* Wh2  = (const float*)d_in[13];
    const float* bh2  = (const float*)d_in[14];
    float* out = (float*)d_out;

    int N = in_sizes[2];
    int E = in_sizes[1] / 2;
    int M = E + N;
    int G = out_size;
    int nbk = (N + 255) >> 8;
    int nchunk = (M + CHUNK - 1) / CHUNK;
    int nlin = (N + 15) / 16;   // 4 nodes/wave x 4 waves

    char* p = (char*)d_ws;
    auto alloc = [&](size_t bytes) -> void* {
        void* r = (void*)p;
        p += (bytes + 255) & ~(size_t)255;
        return r;
    };
    float* asp     = (float*)alloc((size_t)N * NH1 * 4);    // [N][4] node-major logits
    float* adp     = (float*)alloc((size_t)N * NH1 * 4);    // [N][4]
    __half2* h2h   = (__half2*)alloc((size_t)N * 16 * 4);   // N x 32 fp16
    float* as2     = (float*)alloc((size_t)N * 4);
    float* ad2     = (float*)alloc((size_t)N * 4);
    float* out2    = (float*)alloc((size_t)N * C2 * 4);
    int*   offsets = (int*)alloc((size_t)(N + 1) * 4);
    int*   elist   = (int*)alloc((size_t)M * 4);
    int*   cursors = (int*)alloc(256 * 4);
    int*   buckets = (int*)alloc((size_t)nbk * CAP * 4);

    hipMemsetAsync(cursors, 0, 256 * 4, stream);
    k_front<<<nchunk + nlin, 256, 0, stream>>>(ei, E, N, nchunk, cursors, buckets,
                                               x, (const float2*)W1, (const float2*)aS1,
                                               (const float2*)aD1, asp, adp);
    k_build<<<2 * nbk, 256, 0, stream>>>(buckets, cursors, N, M, offsets, elist);
    int nblk16 = (N + 15) / 16;
    k_pass<<<nblk16, 256, 0, stream>>>(offsets, elist, (const float4*)asp,
                                       (const float4*)adp, (const float4*)x, N,
                                       b1, (const float2*)W1, (const float4*)W2,
                                       aS2, aD2, h2h, as2, ad2);
    k_agg2<<<nblk16, 256, 0, stream>>>(offsets, elist, (const char*)as2, ad2,
                                       (const char*)h2h, b2, N, out2);
    k_pool<<<G, 256, 0, stream>>>(out2, batch, N, Wh1, bh1, Wh2, bh2, out);
}